// Round 1
// baseline (1592.254 us; speedup 1.0000x reference)
//
#include <hip/hip_runtime.h>
#include <hip/hip_bf16.h>
#include <stdint.h>

#define TOKENS 32768
#define HIDDEN 2048
#define INTER  1408
#define NEXP   16

typedef unsigned short u16;
typedef __bf16 bf16x8  __attribute__((ext_vector_type(8)));
typedef float  floatx16 __attribute__((ext_vector_type(16)));

// async global->LDS, 16B per lane; LDS dest = wave-uniform base + lane*16
#define GLOAD_LDS(g, l) __builtin_amdgcn_global_load_lds( \
    (const __attribute__((address_space(1))) void*)(g),    \
    (__attribute__((address_space(3))) void*)(l), 16, 0, 0)

__device__ __forceinline__ u16 f2bf(float f) {
    uint32_t u = __builtin_bit_cast(uint32_t, f);
    u = (u + 0x7FFFu + ((u >> 16) & 1u)) >> 16;   // round-to-nearest-even
    return (u16)u;
}

// ---------------- elementwise fp32 -> bf16 (x) ----------------
__global__ void convert_x(const float* __restrict__ src, u16* __restrict__ dst) {
    int idx = blockIdx.x * blockDim.x + threadIdx.x;   // one float4 per thread
    float4 v = ((const float4*)src)[idx];
    ushort4 o;
    o.x = f2bf(v.x); o.y = f2bf(v.y); o.z = f2bf(v.z); o.w = f2bf(v.w);
    ((ushort4*)dst)[idx] = o;
}

// ------------- transpose+convert: src fp32 [E][R][C] -> dst bf16 [E][C][R] -------------
__global__ void transpose_cvt(const float* __restrict__ src, u16* __restrict__ dst,
                              int R, int C) {
    __shared__ float tile[32][33];
    const int e  = blockIdx.z;
    const float* s = src + (size_t)e * R * C;
    u16*         d = dst + (size_t)e * R * C;
    const int r0 = blockIdx.y * 32, c0 = blockIdx.x * 32;
    const int tid = threadIdx.x;
#pragma unroll
    for (int p = 0; p < 4; ++p) {
        int t = p * 256 + tid;
        int sr = t >> 5, sc = t & 31;
        tile[sr][sc] = s[(size_t)(r0 + sr) * C + (c0 + sc)];
    }
    __syncthreads();
#pragma unroll
    for (int p = 0; p < 4; ++p) {
        int t = p * 256 + tid;
        int dr = t >> 5, dc = t & 31;                  // dr: col idx, dc: row idx
        d[(size_t)(c0 + dr) * R + (r0 + dc)] = f2bf(tile[dc][dr]);
    }
}

// ---------------- fused gate+up GEMM + SwiGLU -> h (bf16) ----------------
// A = xb [T][H] bf16 (K-contig), B = wgb/wub [E][I][H] bf16 (N-major, K-contig)
// block tile 128x128, BK=32, 4 waves each 64x64 via 2x2 mfma_32x32x16_bf16
__global__ __launch_bounds__(256, 2)
void gemm_gateup(const u16* __restrict__ xb, const u16* __restrict__ wgb,
                 const u16* __restrict__ wub, const int* __restrict__ gsz,
                 u16* __restrict__ hbuf) {
    __shared__ __align__(16) u16 As[128 * 32];
    __shared__ __align__(16) u16 Bgs[128 * 32];
    __shared__ __align__(16) u16 Bus[128 * 32];

    const int tid  = threadIdx.x;
    const int wave = tid >> 6;
    const int lane = tid & 63;
    const int row0 = blockIdx.y * 128;
    const int col0 = blockIdx.x * 128;

    // expert for this row-block (assumes group boundaries 128-aligned; true here: 2048 each)
    int e = 0, cum = 0;
    for (int i = 0; i < NEXP; ++i) {
        int s = gsz[i];
        if (row0 >= cum + s) cum += s; else { e = i; break; }
    }

    // staging: per buffer 512 16B-segments; wave w stages segs [w*128, w*128+128)
    const int seg0 = wave * 128 + lane;
    const int seg1 = seg0 + 64;
    const int m0 = seg0 >> 2, k80 = (seg0 & 3) * 8;
    const int m1 = seg1 >> 2, k81 = (seg1 & 3) * 8;

    const u16* pA0 = xb + (size_t)(row0 + m0) * HIDDEN + k80;
    const u16* pA1 = xb + (size_t)(row0 + m1) * HIDDEN + k81;
    const size_t wb = (size_t)e * INTER + col0;
    const u16* pG0 = wgb + (wb + m0) * HIDDEN + k80;
    const u16* pG1 = wgb + (wb + m1) * HIDDEN + k81;
    const u16* pU0 = wub + (wb + m0) * HIDDEN + k80;
    const u16* pU1 = wub + (wb + m1) * HIDDEN + k81;

    u16* lA0 = As  + (size_t)(wave * 128) * 8;   u16* lA1 = lA0 + 64 * 8;
    u16* lG0 = Bgs + (size_t)(wave * 128) * 8;   u16* lG1 = lG0 + 64 * 8;
    u16* lU0 = Bus + (size_t)(wave * 128) * 8;   u16* lU1 = lU0 + 64 * 8;

    const int wm = (wave >> 1) * 64;
    const int wn = (wave & 1) * 64;
    const int lm = lane & 31;
    const int lk = (lane >> 5) * 8;

    floatx16 zero;
#pragma unroll
    for (int i = 0; i < 16; ++i) zero[i] = 0.f;
    floatx16 ag[2][2], au[2][2];
#pragma unroll
    for (int i = 0; i < 2; ++i)
#pragma unroll
        for (int j = 0; j < 2; ++j) { ag[i][j] = zero; au[i][j] = zero; }

    for (int it = 0; it < HIDDEN / 32; ++it) {
        GLOAD_LDS(pA0, lA0); GLOAD_LDS(pA1, lA1);
        GLOAD_LDS(pG0, lG0); GLOAD_LDS(pG1, lG1);
        GLOAD_LDS(pU0, lU0); GLOAD_LDS(pU1, lU1);
        __syncthreads();
#pragma unroll
        for (int ks = 0; ks < 2; ++ks) {
            const int ko = ks * 16 + lk;
            bf16x8 a[2], bg[2], bu[2];
#pragma unroll
            for (int i = 0; i < 2; ++i) {
                a[i]  = *(const bf16x8*)(As  + (wm + i * 32 + lm) * 32 + ko);
                bg[i] = *(const bf16x8*)(Bgs + (wn + i * 32 + lm) * 32 + ko);
                bu[i] = *(const bf16x8*)(Bus + (wn + i * 32 + lm) * 32 + ko);
            }
#pragma unroll
            for (int i = 0; i < 2; ++i)
#pragma unroll
                for (int j = 0; j < 2; ++j) {
                    ag[i][j] = __builtin_amdgcn_mfma_f32_32x32x16_bf16(a[i], bg[j], ag[i][j], 0, 0, 0);
                    au[i][j] = __builtin_amdgcn_mfma_f32_32x32x16_bf16(a[i], bu[j], au[i][j], 0, 0, 0);
                }
        }
        __syncthreads();
        pA0 += 32; pA1 += 32; pG0 += 32; pG1 += 32; pU0 += 32; pU1 += 32;
    }

    // epilogue: silu(gate)*up -> bf16 h.  C/D: col=lane&31, row=(r&3)+8*(r>>2)+4*(lane>>5)
    const int rb = 4 * (lane >> 5);
#pragma unroll
    for (int i = 0; i < 2; ++i)
#pragma unroll
        for (int j = 0; j < 2; ++j)
#pragma unroll
            for (int r = 0; r < 16; ++r) {
                int rr = wm + i * 32 + rb + (r & 3) + 8 * (r >> 2);
                int cc = wn + j * 32 + lm;
                float g = ag[i][j][r], u = au[i][j][r];
                float h = (g / (1.f + __expf(-g))) * u;
                hbuf[(size_t)(row0 + rr) * INTER + (col0 + cc)] = f2bf(h);
            }
}

// ---------------- down GEMM: out = h @ w_down (fp32 out) ----------------
// A = hbuf [T][I] bf16, B = wdb [E][H][I] bf16 (N-major, K-contig)
__global__ __launch_bounds__(256, 2)
void gemm_down(const u16* __restrict__ hbuf, const u16* __restrict__ wdb,
               const int* __restrict__ gsz, float* __restrict__ out) {
    __shared__ __align__(16) u16 As[128 * 32];
    __shared__ __align__(16) u16 Bs[128 * 32];

    const int tid  = threadIdx.x;
    const int wave = tid >> 6;
    const int lane = tid & 63;
    const int row0 = blockIdx.y * 128;
    const int col0 = blockIdx.x * 128;

    int e = 0, cum = 0;
    for (int i = 0; i < NEXP; ++i) {
        int s = gsz[i];
        if (row0 >= cum + s) cum += s; else { e = i; break; }
    }

    const int seg0 = wave * 128 + lane;
    const int seg1 = seg0 + 64;
    const int m0 = seg0 >> 2, k80 = (seg0 & 3) * 8;
    const int m1 = seg1 >> 2, k81 = (seg1 & 3) * 8;

    const u16* pA0 = hbuf + (size_t)(row0 + m0) * INTER + k80;
    const u16* pA1 = hbuf + (size_t)(row0 + m1) * INTER + k81;
    const size_t wb = (size_t)e * HIDDEN + col0;
    const u16* pB0 = wdb + (wb + m0) * INTER + k80;
    const u16* pB1 = wdb + (wb + m1) * INTER + k81;

    u16* lA0 = As + (size_t)(wave * 128) * 8;  u16* lA1 = lA0 + 64 * 8;
    u16* lB0 = Bs + (size_t)(wave * 128) * 8;  u16* lB1 = lB0 + 64 * 8;

    const int wm = (wave >> 1) * 64;
    const int wn = (wave & 1) * 64;
    const int lm = lane & 31;
    const int lk = (lane >> 5) * 8;

    floatx16 zero;
#pragma unroll
    for (int i = 0; i < 16; ++i) zero[i] = 0.f;
    floatx16 ac[2][2];
#pragma unroll
    for (int i = 0; i < 2; ++i)
#pragma unroll
        for (int j = 0; j < 2; ++j) ac[i][j] = zero;

    for (int it = 0; it < INTER / 32; ++it) {
        GLOAD_LDS(pA0, lA0); GLOAD_LDS(pA1, lA1);
        GLOAD_LDS(pB0, lB0); GLOAD_LDS(pB1, lB1);
        __syncthreads();
#pragma unroll
        for (int ks = 0; ks < 2; ++ks) {
            const int ko = ks * 16 + lk;
            bf16x8 a[2], b[2];
#pragma unroll
            for (int i = 0; i < 2; ++i) {
                a[i] = *(const bf16x8*)(As + (wm + i * 32 + lm) * 32 + ko);
                b[i] = *(const bf16x8*)(Bs + (wn + i * 32 + lm) * 32 + ko);
            }
#pragma unroll
            for (int i = 0; i < 2; ++i)
#pragma unroll
                for (int j = 0; j < 2; ++j)
                    ac[i][j] = __builtin_amdgcn_mfma_f32_32x32x16_bf16(a[i], b[j], ac[i][j], 0, 0, 0);
        }
        __syncthreads();
        pA0 += 32; pA1 += 32; pB0 += 32; pB1 += 32;
    }

    const int rb = 4 * (lane >> 5);
#pragma unroll
    for (int i = 0; i < 2; ++i)
#pragma unroll
        for (int j = 0; j < 2; ++j)
#pragma unroll
            for (int r = 0; r < 16; ++r) {
                int rr = wm + i * 32 + rb + (r & 3) + 8 * (r >> 2);
                int cc = wn + j * 32 + lm;
                out[(size_t)(row0 + rr) * HIDDEN + (col0 + cc)] = ac[i][j][r];
            }
}

extern "C" void kernel_launch(void* const* d_in, const int* in_sizes, int n_in,
                              void* d_out, int out_size, void* d_ws, size_t ws_size,
                              hipStream_t stream) {
    const float* x  = (const float*)d_in[0];
    const float* wg = (const float*)d_in[1];
    const float* wu = (const float*)d_in[2];
    const float* wd = (const float*)d_in[3];
    const int*  gsz = (const int*)d_in[4];
    float* out = (float*)d_out;

    // workspace layout (bf16 buffers), total ~480 MiB
    const size_t XB_BYTES = (size_t)TOKENS * HIDDEN * 2;          // 134,217,728
    const size_t W_BYTES  = (size_t)NEXP * HIDDEN * INTER * 2;    //  92,274,688
    char* ws = (char*)d_ws;
    u16* xb   = (u16*)(ws);
    u16* wgb  = (u16*)(ws + XB_BYTES);
    u16* wub  = (u16*)(ws + XB_BYTES + W_BYTES);
    u16* wdb  = (u16*)(ws + XB_BYTES + 2 * W_BYTES);
    u16* hbuf = (u16*)(ws + XB_BYTES + 3 * W_BYTES);

    convert_x<<<(TOKENS * HIDDEN) / (4 * 256), 256, 0, stream>>>(x, xb);

    dim3 tg(INTER / 32, HIDDEN / 32, NEXP);   // w_gate/w_up: [E][H][I] -> [E][I][H]
    transpose_cvt<<<tg, 256, 0, stream>>>(wg, wgb, HIDDEN, INTER);
    transpose_cvt<<<tg, 256, 0, stream>>>(wu, wub, HIDDEN, INTER);
    dim3 td(HIDDEN / 32, INTER / 32, NEXP);   // w_down: [E][I][H] -> [E][H][I]
    transpose_cvt<<<td, 256, 0, stream>>>(wd, wdb, INTER, HIDDEN);

    gemm_gateup<<<dim3(INTER / 128, TOKENS / 128), 256, 0, stream>>>(xb, wgb, wub, gsz, hbuf);
    gemm_down<<<dim3(HIDDEN / 128, TOKENS / 128), 256, 0, stream>>>(hbuf, wdb, gsz, out);
}